// Round 10
// baseline (133.852 us; speedup 1.0000x reference)
//
#include <hip/hip_runtime.h>
#include <cmath>

#define NB   2048
#define ND   512
#define NL   8
#define NLAB 128
#define MAXM 64
#define TOPK_ 5
#define NTH  256
#define MAXSLOT 9            // ceil(64*65/2 / 256)
#define GSTRIDE (MAXM*MAXM)  // 4096-float region per (label,layer) gram (compact-used)

// ---------------------------------------------------------------------------
// R21. R20 post-mortem: compact-G neutral -> G traffic off critical path.
// k_gram invariant at ~43us across all round/block shapes. Quantified model:
// 41MB logical / 43.5us = 950GB/s logical, 427GB/s HBM = 7% of machine, no
// queueing -> LATENCY-bound with too few requests in flight (each block
// exposes only 8KB of loads per round, then stalls at a barrier; need ~3.8MB
// in flight device-wide to saturate). Fix: per staging slot, prefetch the
// ENTIRE 2KB row into 4 register banks (A..D) at the block prologue -- all
// 32 float4 loads in flight at once; rounds become {store bank r, barrier,
// compute, barrier}. vmcnt drains oldest-first so round r waits only on
// bank r. Bit-exact: identical LDS contents per round, identical FMA order;
// feats is read-only. +96 VGPR (~170 tot) -> 2 blocks/CU; in-flight bytes/CU
// 32KB -> 64KB. k_pairdec/k_final: R20-verbatim (compact-G).
// ---------------------------------------------------------------------------
#define SLOT_DECL(s) int off##s = -1; int lds##s = 0; \
    float4 pA##s, pB##s, pC##s, pD##s;
#define SLOT_SETUP(s) { int idx = tid + (s)*NTH; if (idx < (m << 5)) { \
    int i = idx >> 5, k4 = idx & 31; \
    off##s = (g_s[i] << 9) + (k4 << 2); \
    lds##s = i * 132 + (k4 << 2); } }
#define SLOT_LOADALL(s) if (off##s >= 0) { \
    pA##s = *(const float4*)(X + off##s); \
    pB##s = *(const float4*)(X + off##s + 128); \
    pC##s = *(const float4*)(X + off##s + 256); \
    pD##s = *(const float4*)(X + off##s + 384); }
#define SLOT_STORE_A(s) if (off##s >= 0) *(float4*)(XtF + lds##s) = pA##s;
#define SLOT_STORE_B(s) if (off##s >= 0) *(float4*)(XtF + lds##s) = pB##s;
#define SLOT_STORE_C(s) if (off##s >= 0) *(float4*)(XtF + lds##s) = pC##s;
#define SLOT_STORE_D(s) if (off##s >= 0) *(float4*)(XtF + lds##s) = pD##s;

__global__ __launch_bounds__(NTH) void k_gram(
    const float* __restrict__ feats, const int* __restrict__ labels,
    float* __restrict__ G, int* __restrict__ cnt,
    unsigned long long* __restrict__ insub)
{
    __shared__ int wsum[4];
    __shared__ int g_s[MAXM];
    __shared__ float Xt[MAXM][132];   // chunk staging; reused as 64x65 gram tile
    __shared__ float rinvp[64];
    __shared__ unsigned long long tops_s[64];
    __shared__ unsigned char keep_s[64];
    float* XtF = &Xt[0][0];
    int c = blockIdx.x, l = blockIdx.y, tid = threadIdx.x;
    int lane = tid & 63, wv = tid >> 6;

    // ---- bucket via register-bitmask wave scan (deterministic) ----
    int base_i = tid * 8;
    unsigned mask = 0u;
    #pragma unroll
    for (int t = 0; t < 8; ++t)
        if (labels[base_i + t] == c) mask |= (1u << t);
    int n = __popc(mask);
    int scan = n;
    #pragma unroll
    for (int off = 1; off < 64; off <<= 1) {
        int v = __shfl_up(scan, off);
        if (lane >= off) scan += v;
    }
    if (lane == 63) wsum[wv] = scan;
    __syncthreads();
    int w0 = wsum[0], w1 = wsum[1], w2 = wsum[2], w3 = wsum[3];
    int m = w0 + w1 + w2 + w3; if (m > MAXM) m = MAXM;
    int base = (wv > 0 ? w0 : 0) + (wv > 1 ? w1 : 0) + (wv > 2 ? w2 : 0);
    int excl = base + scan - n;
    #pragma unroll
    for (int t = 0; t < 8; ++t) {
        if ((mask >> t) & 1u) {
            int slot = excl + __popc(mask & ((1u << t) - 1u));
            if (slot < MAXM) g_s[slot] = base_i + t;
        }
    }
    if (l == 0 && tid == 0) cnt[c] = m;
    __syncthreads();
    if (m == 0) {
        if (l == 7 && tid == 0) insub[c] = 0ull;
        return;
    }

    const float* X = feats + (size_t)l * NB * ND;

    // ---- staging slots; issue the ENTIRE row (4 banks) immediately ----
    SLOT_DECL(0) SLOT_DECL(1) SLOT_DECL(2) SLOT_DECL(3)
    SLOT_DECL(4) SLOT_DECL(5) SLOT_DECL(6) SLOT_DECL(7)
    SLOT_SETUP(0) SLOT_SETUP(1) SLOT_SETUP(2) SLOT_SETUP(3)
    SLOT_SETUP(4) SLOT_SETUP(5) SLOT_SETUP(6) SLOT_SETUP(7)
    SLOT_LOADALL(0) SLOT_LOADALL(1) SLOT_LOADALL(2) SLOT_LOADALL(3)
    SLOT_LOADALL(4) SLOT_LOADALL(5) SLOT_LOADALL(6) SLOT_LOADALL(7)

    // ---- triangular pair-slot decode, statically unrolled (VGPR) ----
    const int P = m * (m + 1) / 2;
    float acc0[MAXSLOT], acc1[MAXSLOT];
    int   ii_[MAXSLOT], jj_[MAXSLOT];
    #pragma unroll
    for (int s = 0; s < MAXSLOT; ++s) {
        int p = tid + s * NTH;
        int iv = -1, jv = 0;
        if (p < P) {
            int i = (int)((sqrtf(8.0f * (float)p + 1.0f) - 1.0f) * 0.5f);
            while (((i + 1) * (i + 2)) / 2 <= p) ++i;
            while ((i * (i + 1)) / 2 > p) --i;
            iv = i; jv = p - (i * (i + 1)) / 2;
        }
        ii_[s] = iv; jj_[s] = jv;
        acc0[s] = 0.0f; acc1[s] = 0.0f;
    }

    // ---- compute body (identical FMA order to R13/R17) ----
    #define COMPUTE_CHUNK \
        _Pragma("unroll") \
        for (int s = 0; s < MAXSLOT; ++s) { \
            if (ii_[s] >= 0) { \
                const float* ra = &Xt[ii_[s]][0]; \
                const float* rb = &Xt[jj_[s]][0]; \
                float a0 = acc0[s], a1 = acc1[s]; \
                _Pragma("unroll") \
                for (int k4 = 0; k4 < 32; ++k4) { \
                    float4 a = *(const float4*)(ra + (k4 << 2)); \
                    float4 b = *(const float4*)(rb + (k4 << 2)); \
                    a0 = fmaf(a.x, b.x, a0); a1 = fmaf(a.y, b.y, a1); \
                    a0 = fmaf(a.z, b.z, a0); a1 = fmaf(a.w, b.w, a1); \
                } \
                acc0[s] = a0; acc1[s] = a1; \
            } \
        }

    // round 0 (bank A: k 0..127)
    SLOT_STORE_A(0) SLOT_STORE_A(1) SLOT_STORE_A(2) SLOT_STORE_A(3)
    SLOT_STORE_A(4) SLOT_STORE_A(5) SLOT_STORE_A(6) SLOT_STORE_A(7)
    __syncthreads();
    COMPUTE_CHUNK
    __syncthreads();
    // round 1 (bank B: k 128..255)
    SLOT_STORE_B(0) SLOT_STORE_B(1) SLOT_STORE_B(2) SLOT_STORE_B(3)
    SLOT_STORE_B(4) SLOT_STORE_B(5) SLOT_STORE_B(6) SLOT_STORE_B(7)
    __syncthreads();
    COMPUTE_CHUNK
    __syncthreads();
    // round 2 (bank C: k 256..383)
    SLOT_STORE_C(0) SLOT_STORE_C(1) SLOT_STORE_C(2) SLOT_STORE_C(3)
    SLOT_STORE_C(4) SLOT_STORE_C(5) SLOT_STORE_C(6) SLOT_STORE_C(7)
    __syncthreads();
    COMPUTE_CHUNK
    __syncthreads();
    // round 3 (bank D: k 384..511)
    SLOT_STORE_D(0) SLOT_STORE_D(1) SLOT_STORE_D(2) SLOT_STORE_D(3)
    SLOT_STORE_D(4) SLOT_STORE_D(5) SLOT_STORE_D(6) SLOT_STORE_D(7)
    __syncthreads();
    COMPUTE_CHUNK

    // ---- stage raw tile (reuse Xt), normalize in place ----
    float (*Gs)[65] = (float(*)[65])(&Xt[0][0]);
    __syncthreads();                  // all Xt readers done before overwrite
    #pragma unroll
    for (int s = 0; s < MAXSLOT; ++s) {
        if (ii_[s] >= 0) {
            float v = acc0[s] + acc1[s];
            Gs[ii_[s]][jj_[s]] = v; Gs[jj_[s]][ii_[s]] = v;
        }
    }
    if (tid < m) for (int j = m; j < 64; ++j) Gs[tid][j] = -2.0f;
    __syncthreads();
    if (tid < 64) rinvp[tid] = (tid < m) ? 1.0f / fmaxf(sqrtf(Gs[tid][tid]), 1e-8f) : 0.0f;
    __syncthreads();
    for (int idx = tid; idx < (m << 6); idx += NTH) {
        int i = idx >> 6, j = idx & 63;
        if (j < m) {
            float raw = Gs[i][j];
            Gs[i][j] = fminf(fmaxf(raw * rinvp[i] * rinvp[j], -1.0f), 1.0f);
        }
    }
    __syncthreads();

    // ---- COMPACT write: m rows x qp float4 (qp = pow2 >= ceil(m/4)) ----
    int q = (m + 3) >> 2, lg = 0;
    while ((1 << lg) < q) ++lg;
    int qp = 1 << lg;
    float* Gc = G + ((size_t)l * NLAB + c) * GSTRIDE;
    for (int idx4 = tid; idx4 < (m << lg); idx4 += NTH) {
        int i = idx4 >> lg, j0 = (idx4 & (qp - 1)) << 2;
        *(float4*)(Gc + ((i << lg) << 2) + j0) = *(const float4*)&Gs[i][j0];
    }
    if (l != 7) return;

    // ---------- fused phase-1 (layer-7 blocks), from normalized tile ----
    if (tid < 64) { keep_s[tid] = 0; tops_s[tid] = 0ull; }
    __syncthreads();
    unsigned long long tops = 0ull; bool keep = false;
    if (tid < m) {
        float v0=-1.f,v1=-1.f,v2=-1.f,v3=-1.f,v4=-1.f;
        int i0=0,i1=0,i2=0,i3=0,i4=0, cand=0;
        #pragma unroll 8
        for (int j = 0; j < 64; ++j) {
            float v = Gs[tid][j];          // normalized, or -2 sentinel
            if (v > 0.0f && j != tid) {
                ++cand;
                if      (v > v0) { v4=v3;i4=i3; v3=v2;i3=i2; v2=v1;i2=i1; v1=v0;i1=i0; v0=v;i0=j; }
                else if (v > v1) { v4=v3;i4=i3; v3=v2;i3=i2; v2=v1;i2=i1; v1=v;i1=j; }
                else if (v > v2) { v4=v3;i4=i3; v3=v2;i3=i2; v2=v;i2=j; }
                else if (v > v3) { v4=v3;i4=i3; v3=v;i3=j; }
                else if (v > v4) { v4=v;i4=j; }
            }
        }
        keep = (cand >= TOPK_);
        if (keep) tops = (1ull<<i0)|(1ull<<i1)|(1ull<<i2)|(1ull<<i3)|(1ull<<i4);
        keep_s[tid] = keep ? 1 : 0; tops_s[tid] = tops;
    }
    __syncthreads();
    unsigned long long Mrow = 0ull;
    if (tid < m && keep) {
        for (int j = 0; j < 64; ++j) {
            if (j == tid || !keep_s[j]) continue;
            if (((tops >> j) & 1ull) || ((tops_s[j] >> tid) & 1ull)) Mrow |= (1ull << j);
        }
    }
    if (tid < 64) {
        unsigned long long b = __ballot(Mrow != 0ull);
        if (tid == 0) insub[c] = b;
    }
}

// ---------------------------------------------------------------------------
// Per (label, pair p): load compact tiles p,p+1 + sentinel-refill; decide(p)
// on wave 0 / decide(p+1) on wave 1; masked pair reduce. Bodies R13-exact.
// (R20-verbatim.)
// ---------------------------------------------------------------------------
__global__ __launch_bounds__(NTH) void k_pairdec(
    const float* __restrict__ G, const int* __restrict__ cnt,
    const unsigned long long* __restrict__ insub,
    float* __restrict__ partial)   // [NL-1][NLAB][4]
{
    __shared__ float Gs0[64][65];
    __shared__ float Gs1[64][65];
    __shared__ unsigned long long tops0[64], tops1[64];
    __shared__ unsigned char keep0[64], keep1[64];
    __shared__ unsigned long long M0s[64], M1s[64];
    __shared__ float es[64];
    __shared__ float red[12];      // 4 waves x 3
    int c = blockIdx.x, p = blockIdx.y, tid = threadIdx.x;
    int lane = tid & 63, wv = tid >> 6;
    int m = cnt[c]; if (m > MAXM) m = MAXM;
    unsigned long long sub = insub[c];

    int q = (m + 3) >> 2, lg = 0;
    while ((1 << lg) < q) ++lg;
    int qp = 1 << lg, cols = qp << 2;

    const float* G0 = G + ((size_t)p       * NLAB + c) * GSTRIDE;
    const float* G1 = G + ((size_t)(p + 1) * NLAB + c) * GSTRIDE;
    // sentinel refill for cols >= stored width (identical -2.0f as before)
    if (cols < 64) {
        for (int idx = tid; idx < (m << 6); idx += NTH) {
            int i = idx >> 6, j = idx & 63;
            if (j >= cols) { Gs0[i][j] = -2.0f; Gs1[i][j] = -2.0f; }
        }
    }
    // compact tile load (m rows x qp float4 each)
    for (int idx4 = tid; idx4 < (m << lg); idx4 += NTH) {
        int i = idx4 >> lg, j0 = (idx4 & (qp - 1)) << 2;
        *(float4*)&Gs0[i][j0] = *(const float4*)(G0 + ((i << lg) << 2) + j0);
        *(float4*)&Gs1[i][j0] = *(const float4*)(G1 + ((i << lg) << 2) + j0);
    }
    if (tid < 64)       { keep0[tid] = 0; tops0[tid] = 0ull; }
    else if (tid < 128) { keep1[tid - 64] = 0; tops1[tid - 64] = 0ull; }
    __syncthreads();

    // ---- decide: wave 0 -> layer p (also ema), wave 1 -> layer p+1 ----
    unsigned long long tops = 0ull; bool keep = false;
    if (wv < 2 && lane < m) {
        const float (*Gt)[65] = (wv == 0) ? Gs0 : Gs1;
        bool act = (sub >> lane) & 1ull;
        float emaval = 0.0f;
        if (act) {
            float v0=-1.f,v1=-1.f,v2=-1.f,v3=-1.f,v4=-1.f;
            int i0=0,i1=0,i2=0,i3=0,i4=0, cand=0, dg=0;
            float rs = 0.0f;
            for (int j = 0; j < 64; ++j) {
                float v = Gt[lane][j];
                if (!((sub >> j) & 1ull)) v = -2.0f;
                if (v > 0.0f) {
                    rs += v; ++dg;                  // includes j == lane (diag ~ 1.0)
                    if (j != lane) {
                        ++cand;
                        if      (v > v0) { v4=v3;i4=i3; v3=v2;i3=i2; v2=v1;i2=i1; v1=v0;i1=i0; v0=v;i0=j; }
                        else if (v > v1) { v4=v3;i4=i3; v3=v2;i3=i2; v2=v1;i2=i1; v1=v;i1=j; }
                        else if (v > v2) { v4=v3;i4=i3; v3=v2;i3=i2; v2=v;i2=j; }
                        else if (v > v3) { v4=v3;i4=i3; v3=v;i3=j; }
                        else if (v > v4) { v4=v;i4=j; }
                    }
                }
            }
            keep = (cand >= TOPK_);
            if (keep) tops = (1ull<<i0)|(1ull<<i1)|(1ull<<i2)|(1ull<<i3)|(1ull<<i4);
            float deg = (float)(dg > 0 ? dg : 1);
            float score = 1.0f / (1.0f + expf(-rs / deg));
            emaval = 0.45f + 0.1f * score;          // MOM*0.5 + (1-MOM)*score
        }
        if (wv == 0) { keep0[lane] = keep ? 1 : 0; tops0[lane] = tops; es[lane] = emaval; }
        else         { keep1[lane] = keep ? 1 : 0; tops1[lane] = tops; }
    }
    __syncthreads();
    if (wv < 2 && lane < m) {
        const unsigned long long* topsW = (wv == 0) ? tops0 : tops1;
        const unsigned char*     keepW = (wv == 0) ? keep0 : keep1;
        unsigned long long Mrow = 0ull;
        if (keep) {
            for (int j = 0; j < 64; ++j) {
                if (j == lane || !keepW[j]) continue;
                if (((tops >> j) & 1ull) || ((topsW[j] >> lane) & 1ull)) Mrow |= (1ull << j);
            }
        }
        if (wv == 0) M0s[lane] = Mrow; else M1s[lane] = Mrow;
    }
    __syncthreads();

    // ---- masked reduce (identical loop + reduce order to R13) ----
    float fn = 0.0f, fd = 0.0f, fc = 0.0f;
    for (int idx = tid; idx < (m << 6); idx += NTH) {
        int i = idx >> 6, j = idx & 63;
        if (j >= m) continue;
        bool b0 = (M0s[i] >> j) & 1ull;
        bool b1 = (M1s[i] >> j) & 1ull;
        if (b0 | b1) {
            float v0 = b0 ? Gs0[i][j] : 0.0f;   // normalized+clipped in k_gram
            float v1 = b1 ? Gs1[i][j] : 0.0f;
            float w = es[i] * es[j];
            float d = v1 - v0;
            fn = fmaf(d * d, w, fn);
            fd += w;
            fc += 1.0f;
        }
    }
    for (int off = 32; off > 0; off >>= 1) {
        fn += __shfl_down(fn, off);
        fd += __shfl_down(fd, off);
        fc += __shfl_down(fc, off);
    }
    if ((tid & 63) == 0) { red[wv * 3] = fn; red[wv * 3 + 1] = fd; red[wv * 3 + 2] = fc; }
    __syncthreads();
    if (tid == 0) {
        float* dst = partial + ((size_t)p * NLAB + c) * 4;
        dst[0] = red[0] + red[3] + red[6] + red[9];
        dst[1] = red[1] + red[4] + red[7] + red[10];
        dst[2] = red[2] + red[5] + red[8] + red[11];
    }
}

// Single-wave final reduction over 896 private slots (~14 KB, L2-hit).
__global__ void k_final(const float* __restrict__ partial, float* __restrict__ out)
{
    int tid = threadIdx.x;
    float total = 0.0f;
    for (int p = 0; p < NL - 1; ++p) {
        float n = 0.0f, d = 0.0f, cc = 0.0f;
        for (int c = tid; c < NLAB; c += 64) {
            const float* src = partial + ((size_t)p * NLAB + c) * 4;
            n += src[0]; d += src[1]; cc += src[2];
        }
        for (int off = 32; off > 0; off >>= 1) {
            n += __shfl_down(n, off);
            d += __shfl_down(d, off);
            cc += __shfl_down(cc, off);
        }
        if (tid == 0 && cc > 0.0f) total += n / fmaxf(d, 1e-8f);
    }
    if (tid == 0) out[0] = 16.0f * total / 7.0f;   // LAMBDA_ALIGN_K * sum / (L-1)
}

extern "C" void kernel_launch(void* const* d_in, const int* in_sizes, int n_in,
                              void* d_out, int out_size, void* d_ws, size_t ws_size,
                              hipStream_t stream) {
    const float* feats  = (const float*)d_in[0];
    const int*   labels = (const int*)d_in[1];
    // (sample_ids unused by the reference)
    char* w = (char*)d_ws;
    size_t gbytes = (size_t)NL * NLAB * GSTRIDE * 4;                 // 16,777,216
    float*    G       = (float*)(w);                                 // compact normalized grams
    float*    partial = (float*)(w + gbytes);                        // 14,336 B
    int*      cnt     = (int*)(w + gbytes + 14336);                  // 512 B
    unsigned long long* insub = (unsigned long long*)(w + gbytes + 14848);   // 1,024 B
    float*    out     = (float*)d_out;

    k_gram   <<<dim3(NLAB, NL),     NTH, 0, stream>>>(feats, labels, G, cnt, insub);
    k_pairdec<<<dim3(NLAB, NL - 1), NTH, 0, stream>>>(G, cnt, insub, partial);
    k_final  <<<1, 64, 0, stream>>>(partial, out);
}

// Round 11
// 129.716 us; speedup vs baseline: 1.0319x; 1.0319x over previous
//
#include <hip/hip_runtime.h>
#include <cmath>

#define NB   2048
#define ND   512
#define NL   8
#define NLAB 128
#define MAXM 64
#define TOPK_ 5
#define NTH  256
#define GSTRIDE (MAXM*MAXM)  // 4096-float region per (label,layer) gram (compact-used)

// ---------------------------------------------------------------------------
// R22. R21 post-mortem: compiler sank the 4-bank prefetch (VGPR 92, not 170)
// -> concurrency experiment void. New quantified model: COMPUTE_CHUNK issues
// ~192 ds_read_b128 wave-instrs/block/round (2 LDS reads per 8 FMAs); at
// 12-18cyc each x 4 blocks/CU sharing the LDS pipe x 4 rounds ~= 25-45us ->
// k_gram is LDS-READ-THROUGHPUT bound. Fix: R12's 2x2 pair tile (TCOMP):
// 4 row-loads feed 4 pairs = 16 FMAs -> 2x fewer LDS reads per FLOP. R12
// PASSED absmax 0.0 with these exact macros (slow there due to grid shape,
// not numerics): per-pair FMA order and final a+b add are bit-identical;
// diag-tile duplicate writes are bitwise-equal. All else R20-verbatim.
// ---------------------------------------------------------------------------
#define SLOT_DECL(s) int off##s = -1; int lds##s = 0; float4 pre##s;
#define SLOT_INIT(s) { int idx = tid + (s)*NTH; if (idx < (m << 5)) { \
    int i = idx >> 5, k4 = idx & 31; \
    off##s = (g_s[i] << 9) + (k4 << 2); \
    lds##s = i * 132 + (k4 << 2); \
    pre##s = *(const float4*)(X + off##s); } }
#define SLOT_STORE(s) if (off##s >= 0) *(float4*)(XtF + lds##s) = pre##s;
#define SLOT_FETCH(s, kcn) if (off##s >= 0) pre##s = *(const float4*)(X + off##s + (kcn));

// 2x2 pair-tile slots (R12-proven; static names, VGPR-resident).
#define MAXTSLOT 3           // ceil(32*33/2 / 256)
#define TDECL(s) int ti##s = -1, tj##s = 0; \
    float q##s##00a=0.f,q##s##00b=0.f,q##s##01a=0.f,q##s##01b=0.f, \
          q##s##10a=0.f,q##s##10b=0.f,q##s##11a=0.f,q##s##11b=0.f;

#define TSETUP(s) { int p = tid + (s)*NTH; if (p < TP) { \
    int i = (int)((sqrtf(8.0f * (float)p + 1.0f) - 1.0f) * 0.5f); \
    while (((i + 1) * (i + 2)) / 2 <= p) ++i; \
    while ((i * (i + 1)) / 2 > p) --i; \
    ti##s = i; tj##s = p - (i * (i + 1)) / 2; } }

#define TCOMP(s) if (ti##s >= 0) { \
    const float* ra = XtF + (ti##s << 1) * 132; \
    const float* rb = XtF + (tj##s << 1) * 132; \
    _Pragma("unroll") \
    for (int k4 = 0; k4 < 32; ++k4) { \
        float4 a0v = *(const float4*)(ra + (k4 << 2)); \
        float4 a1v = *(const float4*)(ra + 132 + (k4 << 2)); \
        float4 b0v = *(const float4*)(rb + (k4 << 2)); \
        float4 b1v = *(const float4*)(rb + 132 + (k4 << 2)); \
        q##s##00a = fmaf(a0v.x, b0v.x, q##s##00a); q##s##00b = fmaf(a0v.y, b0v.y, q##s##00b); \
        q##s##00a = fmaf(a0v.z, b0v.z, q##s##00a); q##s##00b = fmaf(a0v.w, b0v.w, q##s##00b); \
        q##s##01a = fmaf(a0v.x, b1v.x, q##s##01a); q##s##01b = fmaf(a0v.y, b1v.y, q##s##01b); \
        q##s##01a = fmaf(a0v.z, b1v.z, q##s##01a); q##s##01b = fmaf(a0v.w, b1v.w, q##s##01b); \
        q##s##10a = fmaf(a1v.x, b0v.x, q##s##10a); q##s##10b = fmaf(a1v.y, b0v.y, q##s##10b); \
        q##s##10a = fmaf(a1v.z, b0v.z, q##s##10a); q##s##10b = fmaf(a1v.w, b0v.w, q##s##10b); \
        q##s##11a = fmaf(a1v.x, b1v.x, q##s##11a); q##s##11b = fmaf(a1v.y, b1v.y, q##s##11b); \
        q##s##11a = fmaf(a1v.z, b1v.z, q##s##11a); q##s##11b = fmaf(a1v.w, b1v.w, q##s##11b); \
    } }

// Symmetric write-back; diag-tile duplicates are bitwise-identical (R12).
#define TWB(s) if (ti##s >= 0) { \
    int ib = ti##s << 1, jb = tj##s << 1; \
    float v00 = q##s##00a + q##s##00b; \
    float v01 = q##s##01a + q##s##01b; \
    float v10 = q##s##10a + q##s##10b; \
    float v11 = q##s##11a + q##s##11b; \
    Gs[ib][jb] = v00; Gs[jb][ib] = v00; \
    if (jb + 1 < m) { Gs[ib][jb+1] = v01; Gs[jb+1][ib] = v01; } \
    if (ib + 1 < m) { Gs[ib+1][jb] = v10; Gs[jb][ib+1] = v10; } \
    if (ib + 1 < m && jb + 1 < m) { Gs[ib+1][jb+1] = v11; Gs[jb+1][ib+1] = v11; } }

__global__ __launch_bounds__(NTH) void k_gram(
    const float* __restrict__ feats, const int* __restrict__ labels,
    float* __restrict__ G, int* __restrict__ cnt,
    unsigned long long* __restrict__ insub)
{
    __shared__ int wsum[4];
    __shared__ int g_s[MAXM];
    __shared__ float Xt[MAXM][132];   // staging; reused as 64x65 gram tile
    __shared__ float rinvp[64];
    __shared__ unsigned long long tops_s[64];
    __shared__ unsigned char keep_s[64];
    float* XtF = &Xt[0][0];
    int c = blockIdx.x, l = blockIdx.y, tid = threadIdx.x;
    int lane = tid & 63, wv = tid >> 6;

    // ---- bucket via register-bitmask wave scan (deterministic) ----
    int base_i = tid * 8;
    unsigned mask = 0u;
    #pragma unroll
    for (int t = 0; t < 8; ++t)
        if (labels[base_i + t] == c) mask |= (1u << t);
    int n = __popc(mask);
    int scan = n;
    #pragma unroll
    for (int off = 1; off < 64; off <<= 1) {
        int v = __shfl_up(scan, off);
        if (lane >= off) scan += v;
    }
    if (lane == 63) wsum[wv] = scan;
    __syncthreads();
    int w0 = wsum[0], w1 = wsum[1], w2 = wsum[2], w3 = wsum[3];
    int m = w0 + w1 + w2 + w3; if (m > MAXM) m = MAXM;
    int base = (wv > 0 ? w0 : 0) + (wv > 1 ? w1 : 0) + (wv > 2 ? w2 : 0);
    int excl = base + scan - n;
    #pragma unroll
    for (int t = 0; t < 8; ++t) {
        if ((mask >> t) & 1u) {
            int slot = excl + __popc(mask & ((1u << t) - 1u));
            if (slot < MAXM) g_s[slot] = base_i + t;
        }
    }
    if (l == 0 && tid == 0) cnt[c] = m;
    __syncthreads();
    if (m == 0) {
        if (l == 7 && tid == 0) insub[c] = 0ull;
        return;
    }

    const float* X = feats + (size_t)l * NB * ND;

    // ---- scalar staging slots; prefetch chunk 0 ----
    SLOT_DECL(0) SLOT_DECL(1) SLOT_DECL(2) SLOT_DECL(3)
    SLOT_DECL(4) SLOT_DECL(5) SLOT_DECL(6) SLOT_DECL(7)
    SLOT_INIT(0) SLOT_INIT(1) SLOT_INIT(2) SLOT_INIT(3)
    SLOT_INIT(4) SLOT_INIT(5) SLOT_INIT(6) SLOT_INIT(7)

    // ---- 2x2 tile decode (R=ceil(m/2) triangular) ----
    const int R = (m + 1) >> 1;
    const int TP = R * (R + 1) / 2;
    TDECL(0) TDECL(1) TDECL(2)
    TSETUP(0) TSETUP(1) TSETUP(2)

    // ---- 4-round pipelined K-loop (R13-exact per-pair FMA order) ----
    for (int kc = 0; kc < ND; kc += 128) {
        if (kc) __syncthreads();
        SLOT_STORE(0) SLOT_STORE(1) SLOT_STORE(2) SLOT_STORE(3)
        SLOT_STORE(4) SLOT_STORE(5) SLOT_STORE(6) SLOT_STORE(7)
        __syncthreads();
        if (kc + 128 < ND) {
            int kcn = kc + 128;
            SLOT_FETCH(0, kcn) SLOT_FETCH(1, kcn) SLOT_FETCH(2, kcn) SLOT_FETCH(3, kcn)
            SLOT_FETCH(4, kcn) SLOT_FETCH(5, kcn) SLOT_FETCH(6, kcn) SLOT_FETCH(7, kcn)
        }
        TCOMP(0) TCOMP(1) TCOMP(2)
    }

    // ---- stage raw tile (reuse Xt), normalize in place ----
    float (*Gs)[65] = (float(*)[65])(&Xt[0][0]);
    __syncthreads();                  // all Xt readers done before overwrite
    TWB(0) TWB(1) TWB(2)
    if (tid < m) for (int j = m; j < 64; ++j) Gs[tid][j] = -2.0f;
    __syncthreads();
    if (tid < 64) rinvp[tid] = (tid < m) ? 1.0f / fmaxf(sqrtf(Gs[tid][tid]), 1e-8f) : 0.0f;
    __syncthreads();
    for (int idx = tid; idx < (m << 6); idx += NTH) {
        int i = idx >> 6, j = idx & 63;
        if (j < m) {
            float raw = Gs[i][j];
            Gs[i][j] = fminf(fmaxf(raw * rinvp[i] * rinvp[j], -1.0f), 1.0f);
        }
    }
    __syncthreads();

    // ---- COMPACT write: m rows x qp float4 (qp = pow2 >= ceil(m/4)) ----
    int q = (m + 3) >> 2, lg = 0;
    while ((1 << lg) < q) ++lg;
    int qp = 1 << lg;
    float* Gc = G + ((size_t)l * NLAB + c) * GSTRIDE;
    for (int idx4 = tid; idx4 < (m << lg); idx4 += NTH) {
        int i = idx4 >> lg, j0 = (idx4 & (qp - 1)) << 2;
        *(float4*)(Gc + ((i << lg) << 2) + j0) = *(const float4*)&Gs[i][j0];
    }
    if (l != 7) return;

    // ---------- fused phase-1 (layer-7 blocks), from normalized tile ----
    if (tid < 64) { keep_s[tid] = 0; tops_s[tid] = 0ull; }
    __syncthreads();
    unsigned long long tops = 0ull; bool keep = false;
    if (tid < m) {
        float v0=-1.f,v1=-1.f,v2=-1.f,v3=-1.f,v4=-1.f;
        int i0=0,i1=0,i2=0,i3=0,i4=0, cand=0;
        #pragma unroll 8
        for (int j = 0; j < 64; ++j) {
            float v = Gs[tid][j];          // normalized, or -2 sentinel
            if (v > 0.0f && j != tid) {
                ++cand;
                if      (v > v0) { v4=v3;i4=i3; v3=v2;i3=i2; v2=v1;i2=i1; v1=v0;i1=i0; v0=v;i0=j; }
                else if (v > v1) { v4=v3;i4=i3; v3=v2;i3=i2; v2=v1;i2=i1; v1=v;i1=j; }
                else if (v > v2) { v4=v3;i4=i3; v3=v2;i3=i2; v2=v;i2=j; }
                else if (v > v3) { v4=v3;i4=i3; v3=v;i3=j; }
                else if (v > v4) { v4=v;i4=j; }
            }
        }
        keep = (cand >= TOPK_);
        if (keep) tops = (1ull<<i0)|(1ull<<i1)|(1ull<<i2)|(1ull<<i3)|(1ull<<i4);
        keep_s[tid] = keep ? 1 : 0; tops_s[tid] = tops;
    }
    __syncthreads();
    unsigned long long Mrow = 0ull;
    if (tid < m && keep) {
        for (int j = 0; j < 64; ++j) {
            if (j == tid || !keep_s[j]) continue;
            if (((tops >> j) & 1ull) || ((tops_s[j] >> tid) & 1ull)) Mrow |= (1ull << j);
        }
    }
    if (tid < 64) {
        unsigned long long b = __ballot(Mrow != 0ull);
        if (tid == 0) insub[c] = b;
    }
}

// ---------------------------------------------------------------------------
// Per (label, pair p): load compact tiles p,p+1 + sentinel-refill; decide(p)
// on wave 0 / decide(p+1) on wave 1; masked pair reduce. (R20-verbatim.)
// ---------------------------------------------------------------------------
__global__ __launch_bounds__(NTH) void k_pairdec(
    const float* __restrict__ G, const int* __restrict__ cnt,
    const unsigned long long* __restrict__ insub,
    float* __restrict__ partial)   // [NL-1][NLAB][4]
{
    __shared__ float Gs0[64][65];
    __shared__ float Gs1[64][65];
    __shared__ unsigned long long tops0[64], tops1[64];
    __shared__ unsigned char keep0[64], keep1[64];
    __shared__ unsigned long long M0s[64], M1s[64];
    __shared__ float es[64];
    __shared__ float red[12];      // 4 waves x 3
    int c = blockIdx.x, p = blockIdx.y, tid = threadIdx.x;
    int lane = tid & 63, wv = tid >> 6;
    int m = cnt[c]; if (m > MAXM) m = MAXM;
    unsigned long long sub = insub[c];

    int q = (m + 3) >> 2, lg = 0;
    while ((1 << lg) < q) ++lg;
    int qp = 1 << lg, cols = qp << 2;

    const float* G0 = G + ((size_t)p       * NLAB + c) * GSTRIDE;
    const float* G1 = G + ((size_t)(p + 1) * NLAB + c) * GSTRIDE;
    // sentinel refill for cols >= stored width (identical -2.0f as before)
    if (cols < 64) {
        for (int idx = tid; idx < (m << 6); idx += NTH) {
            int i = idx >> 6, j = idx & 63;
            if (j >= cols) { Gs0[i][j] = -2.0f; Gs1[i][j] = -2.0f; }
        }
    }
    // compact tile load (m rows x qp float4 each)
    for (int idx4 = tid; idx4 < (m << lg); idx4 += NTH) {
        int i = idx4 >> lg, j0 = (idx4 & (qp - 1)) << 2;
        *(float4*)&Gs0[i][j0] = *(const float4*)(G0 + ((i << lg) << 2) + j0);
        *(float4*)&Gs1[i][j0] = *(const float4*)(G1 + ((i << lg) << 2) + j0);
    }
    if (tid < 64)       { keep0[tid] = 0; tops0[tid] = 0ull; }
    else if (tid < 128) { keep1[tid - 64] = 0; tops1[tid - 64] = 0ull; }
    __syncthreads();

    // ---- decide: wave 0 -> layer p (also ema), wave 1 -> layer p+1 ----
    unsigned long long tops = 0ull; bool keep = false;
    if (wv < 2 && lane < m) {
        const float (*Gt)[65] = (wv == 0) ? Gs0 : Gs1;
        bool act = (sub >> lane) & 1ull;
        float emaval = 0.0f;
        if (act) {
            float v0=-1.f,v1=-1.f,v2=-1.f,v3=-1.f,v4=-1.f;
            int i0=0,i1=0,i2=0,i3=0,i4=0, cand=0, dg=0;
            float rs = 0.0f;
            for (int j = 0; j < 64; ++j) {
                float v = Gt[lane][j];
                if (!((sub >> j) & 1ull)) v = -2.0f;
                if (v > 0.0f) {
                    rs += v; ++dg;                  // includes j == lane (diag ~ 1.0)
                    if (j != lane) {
                        ++cand;
                        if      (v > v0) { v4=v3;i4=i3; v3=v2;i3=i2; v2=v1;i2=i1; v1=v0;i1=i0; v0=v;i0=j; }
                        else if (v > v1) { v4=v3;i4=i3; v3=v2;i3=i2; v2=v1;i2=i1; v1=v;i1=j; }
                        else if (v > v2) { v4=v3;i4=i3; v3=v2;i3=i2; v2=v;i2=j; }
                        else if (v > v3) { v4=v3;i4=i3; v3=v;i3=j; }
                        else if (v > v4) { v4=v;i4=j; }
                    }
                }
            }
            keep = (cand >= TOPK_);
            if (keep) tops = (1ull<<i0)|(1ull<<i1)|(1ull<<i2)|(1ull<<i3)|(1ull<<i4);
            float deg = (float)(dg > 0 ? dg : 1);
            float score = 1.0f / (1.0f + expf(-rs / deg));
            emaval = 0.45f + 0.1f * score;          // MOM*0.5 + (1-MOM)*score
        }
        if (wv == 0) { keep0[lane] = keep ? 1 : 0; tops0[lane] = tops; es[lane] = emaval; }
        else         { keep1[lane] = keep ? 1 : 0; tops1[lane] = tops; }
    }
    __syncthreads();
    if (wv < 2 && lane < m) {
        const unsigned long long* topsW = (wv == 0) ? tops0 : tops1;
        const unsigned char*     keepW = (wv == 0) ? keep0 : keep1;
        unsigned long long Mrow = 0ull;
        if (keep) {
            for (int j = 0; j < 64; ++j) {
                if (j == lane || !keepW[j]) continue;
                if (((tops >> j) & 1ull) || ((topsW[j] >> lane) & 1ull)) Mrow |= (1ull << j);
            }
        }
        if (wv == 0) M0s[lane] = Mrow; else M1s[lane] = Mrow;
    }
    __syncthreads();

    // ---- masked reduce (identical loop + reduce order to R13) ----
    float fn = 0.0f, fd = 0.0f, fc = 0.0f;
    for (int idx = tid; idx < (m << 6); idx += NTH) {
        int i = idx >> 6, j = idx & 63;
        if (j >= m) continue;
        bool b0 = (M0s[i] >> j) & 1ull;
        bool b1 = (M1s[i] >> j) & 1ull;
        if (b0 | b1) {
            float v0 = b0 ? Gs0[i][j] : 0.0f;   // normalized+clipped in k_gram
            float v1 = b1 ? Gs1[i][j] : 0.0f;
            float w = es[i] * es[j];
            float d = v1 - v0;
            fn = fmaf(d * d, w, fn);
            fd += w;
            fc += 1.0f;
        }
    }
    for (int off = 32; off > 0; off >>= 1) {
        fn += __shfl_down(fn, off);
        fd += __shfl_down(fd, off);
        fc += __shfl_down(fc, off);
    }
    if ((tid & 63) == 0) { red[wv * 3] = fn; red[wv * 3 + 1] = fd; red[wv * 3 + 2] = fc; }
    __syncthreads();
    if (tid == 0) {
        float* dst = partial + ((size_t)p * NLAB + c) * 4;
        dst[0] = red[0] + red[3] + red[6] + red[9];
        dst[1] = red[1] + red[4] + red[7] + red[10];
        dst[2] = red[2] + red[5] + red[8] + red[11];
    }
}

// Single-wave final reduction over 896 private slots (~14 KB, L2-hit).
__global__ void k_final(const float* __restrict__ partial, float* __restrict__ out)
{
    int tid = threadIdx.x;
    float total = 0.0f;
    for (int p = 0; p < NL - 1; ++p) {
        float n = 0.0f, d = 0.0f, cc = 0.0f;
        for (int c = tid; c < NLAB; c += 64) {
            const float* src = partial + ((size_t)p * NLAB + c) * 4;
            n += src[0]; d += src[1]; cc += src[2];
        }
        for (int off = 32; off > 0; off >>= 1) {
            n += __shfl_down(n, off);
            d += __shfl_down(d, off);
            cc += __shfl_down(cc, off);
        }
        if (tid == 0 && cc > 0.0f) total += n / fmaxf(d, 1e-8f);
    }
    if (tid == 0) out[0] = 16.0f * total / 7.0f;   // LAMBDA_ALIGN_K * sum / (L-1)
}

extern "C" void kernel_launch(void* const* d_in, const int* in_sizes, int n_in,
                              void* d_out, int out_size, void* d_ws, size_t ws_size,
                              hipStream_t stream) {
    const float* feats  = (const float*)d_in[0];
    const int*   labels = (const int*)d_in[1];
    // (sample_ids unused by the reference)
    char* w = (char*)d_ws;
    size_t gbytes = (size_t)NL * NLAB * GSTRIDE * 4;                 // 16,777,216
    float*    G       = (float*)(w);                                 // compact normalized grams
    float*    partial = (float*)(w + gbytes);                        // 14,336 B
    int*      cnt     = (int*)(w + gbytes + 14336);                  // 512 B
    unsigned long long* insub = (unsigned long long*)(w + gbytes + 14848);   // 1,024 B
    float*    out     = (float*)d_out;

    k_gram   <<<dim3(NLAB, NL),     NTH, 0, stream>>>(feats, labels, G, cnt, insub);
    k_pairdec<<<dim3(NLAB, NL - 1), NTH, 0, stream>>>(G, cnt, insub, partial);
    k_final  <<<1, 64, 0, stream>>>(partial, out);
}